// Round 4
// baseline (238.784 us; speedup 1.0000x reference)
//
#include <hip/hip_runtime.h>
#include <hip/hip_bf16.h>

typedef unsigned short u16;
typedef unsigned char u8;
typedef short short8 __attribute__((ext_vector_type(8)));
typedef float floatx4 __attribute__((ext_vector_type(4)));
typedef int intx8 __attribute__((ext_vector_type(8)));
typedef long long i64;

#define BB 4
#define NN 4096
#define CC 256
#define NG 8
#define M_TOT (BB * NN)   // 16384 rows
#define GN_EPS 1e-3f
#define ATT_SCALE 0.0625f // C^-0.5
#define MCONST 2.5f       // fixed softmax offset: keeps p=exp(s'-MCONST) in fp8 normal range
#define UNIT_SCALE 0x7F7F7F7F  // E8M0 127 in every byte -> scale 1.0

__device__ __forceinline__ u16 f2bf(float f) {
  __hip_bfloat16 h = __float2bfloat16(f);
  return __builtin_bit_cast(u16, h);
}
__device__ __forceinline__ float bf2f(u16 u) {
  unsigned int i = ((unsigned int)u) << 16;
  return __builtin_bit_cast(float, i);
}
__device__ __forceinline__ unsigned pack2(float a, float b) {
  return (unsigned)f2bf(a) | ((unsigned)f2bf(b) << 16);
}
// pack 4 floats -> 4 fp8 e4m3 bytes
__device__ __forceinline__ unsigned pk4f8(float a, float b, float c, float d) {
  unsigned v = __builtin_amdgcn_cvt_pk_fp8_f32(a, b, 0, false);
  v = __builtin_amdgcn_cvt_pk_fp8_f32(c, d, v, true);
  return v;
}
__device__ __forceinline__ u8 f8byte(float a) {
  return (u8)(__builtin_amdgcn_cvt_pk_fp8_f32(a, a, 0, false) & 0xFF);
}

typedef __attribute__((address_space(3))) unsigned int lds_u32;
typedef const __attribute__((address_space(1))) unsigned int glb_u32;
#define ASYNC16(g, l) \
  __builtin_amdgcn_global_load_lds((glb_u32*)(g), (lds_u32*)(l), 16, 0, 0)

// ---------------- fused: GN stats partials (blocks 0..511) + weight transpose (512..575) ----
__global__ void prep_stats(const float* __restrict__ x,
                           const float* __restrict__ Wq, const float* __restrict__ Wk,
                           const float* __restrict__ Wv, const float* __restrict__ Wp,
                           float* __restrict__ part,
                           u16* __restrict__ wqT, u16* __restrict__ wkT,
                           u16* __restrict__ wvT, u16* __restrict__ wpT) {
  __shared__ u16 Ts[64][68];
  int blk = blockIdx.x;
  int t = threadIdx.x;
  if (blk < 512) {
    int b = blk >> 7, chunk = blk & 127;
    const float* p = x + ((size_t)b * NN + chunk * 32) * CC + t;
    float s = 0.f, ss = 0.f;
    for (int i = 0; i < 32; ++i) { float v = p[(size_t)i * CC]; s += v; ss += v * v; }
    for (int off = 1; off < 32; off <<= 1) { s += __shfl_xor(s, off); ss += __shfl_xor(ss, off); }
    if ((t & 31) == 0) {
      int g = t >> 5;
      part[((size_t)blk * NG + g) * 2 + 0] = s;
      part[((size_t)blk * NG + g) * 2 + 1] = ss;
    }
  } else {
    int pid = blk - 512;
    int y = pid >> 4, tile = pid & 15;
    int o0 = (tile >> 2) * 64, c0 = (tile & 3) * 64;
    const float* W = (y == 0) ? Wq : (y == 1) ? Wk : (y == 2) ? Wv : Wp;
    u16* WT = (y == 0) ? wqT : (y == 1) ? wkT : (y == 2) ? wvT : wpT;
    int cl = t >> 4, o4 = t & 15;
    for (int it = 0; it < 4; ++it) {
      int c = cl + it * 16;
      float4 v = *reinterpret_cast<const float4*>(W + (size_t)(c0 + c) * CC + o0 + o4 * 4);
      Ts[c][o4 * 4 + 0] = f2bf(v.x); Ts[c][o4 * 4 + 1] = f2bf(v.y);
      Ts[c][o4 * 4 + 2] = f2bf(v.z); Ts[c][o4 * 4 + 3] = f2bf(v.w);
    }
    __syncthreads();
    int ol = t >> 3, c8 = t & 7;
    for (int it = 0; it < 2; ++it) {
      int o = ol + it * 32;
      uint4 uv;
      uv.x = (unsigned)Ts[c8 * 8 + 0][o] | ((unsigned)Ts[c8 * 8 + 1][o] << 16);
      uv.y = (unsigned)Ts[c8 * 8 + 2][o] | ((unsigned)Ts[c8 * 8 + 3][o] << 16);
      uv.z = (unsigned)Ts[c8 * 8 + 4][o] | ((unsigned)Ts[c8 * 8 + 5][o] << 16);
      uv.w = (unsigned)Ts[c8 * 8 + 6][o] | ((unsigned)Ts[c8 * 8 + 7][o] << 16);
      *reinterpret_cast<uint4*>(WT + (size_t)(o0 + o) * CC + c0 + c8 * 8) = uv;
    }
  }
}

// ---------------- GroupNorm: inline finalize (from partials) + apply -> xn bf16 ----------
__global__ __launch_bounds__(256) void gn_apply(
    const float* __restrict__ x, const float* __restrict__ gamma,
    const float* __restrict__ beta, const float* __restrict__ part,
    u16* __restrict__ xnb) {
  __shared__ float gnst[16];
  int blk = blockIdx.x;
  int t = threadIdx.x;
  int b = blk >> 7;                      // 128 blocks per batch
  if (t < 64) {
    int g = t >> 3, j = t & 7;
    float s = 0.f, ss = 0.f;
    for (int ch = j; ch < 128; ch += 8) {
      size_t idx = (((size_t)(b * 128 + ch)) * NG + g) * 2;
      s += part[idx]; ss += part[idx + 1];
    }
    for (int off = 1; off < 8; off <<= 1) { s += __shfl_xor(s, off); ss += __shfl_xor(ss, off); }
    if (j == 0) {
      const float cnt = (float)(NN * (CC / NG));
      float mean = s / cnt;
      float var = ss / cnt - mean * mean;
      gnst[g * 2] = mean;
      gnst[g * 2 + 1] = rsqrtf(var + GN_EPS);
    }
  }
  __syncthreads();
  int row0 = blk * 32;
#pragma unroll
  for (int it = 0; it < 8; ++it) {
    int idx = t + it * 256;              // 0..2047: 32 rows x 64 float4
    int rl = idx >> 6, c4 = idx & 63;
    int g = c4 >> 3;
    float mean = gnst[g * 2], rstd = gnst[g * 2 + 1];
    size_t gidx = (size_t)(row0 + rl) * 64 + c4;
    float4 v = reinterpret_cast<const float4*>(x)[gidx];
    float4 gm = reinterpret_cast<const float4*>(gamma)[c4];
    float4 bt = reinterpret_cast<const float4*>(beta)[c4];
    ushort4 o;
    o.x = f2bf((v.x - mean) * rstd * gm.x + bt.x);
    o.y = f2bf((v.y - mean) * rstd * gm.y + bt.y);
    o.z = f2bf((v.z - mean) * rstd * gm.z + bt.z);
    o.w = f2bf((v.w - mean) * rstd * gm.w + bt.w);
    reinterpret_cast<ushort4*>(xnb)[gidx] = o;
  }
}

// ---------------- fused QKV GEMM (bf16 compute, fp8 outputs) ----------------
// q,k: natural fp8 [B][N][C].
// v: fp8 [B][C=d][N], per 128-token tile permuted so that k-position p holds
//    token key(p) = 16*((p>>2)&7) + 4*(p>>5) + (p&3)  (matches K=128 scaled-MFMA
//    A-fragment packing of P in fa_kernel: kpos 32*hi+4*g+b <-> key 16*g+4*hi+b).
#define LDT 72
__global__ __launch_bounds__(256) void gemm_qkv(
    const u16* __restrict__ xnb,
    const u16* __restrict__ wqT, const u16* __restrict__ wkT, const u16* __restrict__ wvT,
    const float* __restrict__ bq, const float* __restrict__ bk, const float* __restrict__ bv,
    u8* __restrict__ qb, u8* __restrict__ kb, u8* __restrict__ vTb) {
  __shared__ u16 sm[2 * 128 * LDT];
  u16* Asp = sm;
  u16* Bsp = sm + 128 * LDT;
  int m0 = blockIdx.x * 128;
  int widx = blockIdx.y >> 1;
  int n0 = (blockIdx.y & 1) * 128;
  const u16* wT = (widx == 0) ? wqT : (widx == 1) ? wkT : wvT;
  const float* bias = (widx == 0) ? bq : (widx == 1) ? bk : bv;
  int t = threadIdx.x, w = t >> 6, lane = t & 63, lo = lane & 15, hi = lane >> 4;
  int wm = (w >> 1) * 64, wn = (w & 1) * 64;
  floatx4 acc[4][4];
  for (int i = 0; i < 4; ++i) for (int j = 0; j < 4; ++j) acc[i][j] = (floatx4){0.f, 0.f, 0.f, 0.f};
  for (int kt = 0; kt < 4; ++kt) {
    int k0 = kt * 64;
    __syncthreads();
    for (int i = 0; i < 4; ++i) {
      int idx = t + i * 256, r = idx >> 3, c8 = idx & 7;
      *reinterpret_cast<uint4*>(Asp + r * LDT + c8 * 8) =
          *reinterpret_cast<const uint4*>(xnb + (size_t)(m0 + r) * CC + k0 + c8 * 8);
      *reinterpret_cast<uint4*>(Bsp + r * LDT + c8 * 8) =
          *reinterpret_cast<const uint4*>(wT + (size_t)(n0 + r) * CC + k0 + c8 * 8);
    }
    __syncthreads();
    for (int k32 = 0; k32 < 2; ++k32) {
      short8 af[4], bfr[4];
      for (int mt = 0; mt < 4; ++mt)
        af[mt] = *reinterpret_cast<const short8*>(Asp + (wm + mt * 16 + lo) * LDT + k32 * 32 + hi * 8);
      for (int nt = 0; nt < 4; ++nt)
        bfr[nt] = *reinterpret_cast<const short8*>(Bsp + (wn + nt * 16 + lo) * LDT + k32 * 32 + hi * 8);
      for (int mt = 0; mt < 4; ++mt)
        for (int nt = 0; nt < 4; ++nt)
          acc[mt][nt] = __builtin_amdgcn_mfma_f32_16x16x32_bf16(af[mt], bfr[nt], acc[mt][nt], 0, 0, 0);
    }
  }
  __syncthreads();
  for (int mt = 0; mt < 4; ++mt)
    for (int nt = 0; nt < 4; ++nt)
      for (int r = 0; r < 4; ++r) {
        int rr = wm + mt * 16 + hi * 4 + r;
        int cc2 = wn + nt * 16 + lo;
        sm[rr * 130 + cc2] = f2bf(acc[mt][nt][r] + bias[n0 + cc2]);
      }
  __syncthreads();
  if (widx < 2) {
    u8* outp = (widx == 0) ? qb : kb;
    for (int j = 0; j < 8; ++j) {
      int c = t + j * 256;
      int row = c >> 4, chl = c & 15;
      const u16* sp = sm + row * 130 + chl * 8;
      uint2 val;
      val.x = pk4f8(bf2f(sp[0]), bf2f(sp[1]), bf2f(sp[2]), bf2f(sp[3]));
      val.y = pk4f8(bf2f(sp[4]), bf2f(sp[5]), bf2f(sp[6]), bf2f(sp[7]));
      int rowg = m0 + row;
      int chg = (n0 >> 3) + chl;
      *reinterpret_cast<uint2*>(outp + (size_t)rowg * CC + chg * 8) = val;
    }
  } else {
    // V writer: block covers tokens [m0, m0+128) = exactly one 128-key tile.
    // 16B chunk (dloc, u): byte c holds V[key][dglob] with
    //   key = 64*(u&1) + 4*(u>>1) + 16*(c>>2) + (c&3)
    int dloc = t & 127;
    int dglob = n0 + dloc;
    int bb = m0 >> 12, tk = m0 & (NN - 1);
    u8* dst = vTb + ((size_t)(bb * CC + dglob)) * NN + tk;
#pragma unroll
    for (int it = 0; it < 2; ++it) {
      int ub = (t >> 7) * 2 + it * 4;    // {0,4} or {2,6}; covers u=ub,ub+1
      unsigned wds[8];
#pragma unroll
      for (int uo = 0; uo < 2; ++uo) {
        int u = ub + uo;
        int rbase = 64 * (u & 1) + 4 * (u >> 1);
#pragma unroll
        for (int q = 0; q < 4; ++q) {
          int r0 = rbase + q * 16;
          wds[uo * 4 + q] = pk4f8(bf2f(sm[(r0 + 0) * 130 + dloc]), bf2f(sm[(r0 + 1) * 130 + dloc]),
                                  bf2f(sm[(r0 + 2) * 130 + dloc]), bf2f(sm[(r0 + 3) * 130 + dloc]));
        }
      }
      *reinterpret_cast<uint4*>(dst + ub * 16) = (uint4){wds[0], wds[1], wds[2], wds[3]};
      *reinterpret_cast<uint4*>(dst + ub * 16 + 16) = (uint4){wds[4], wds[5], wds[6], wds[7]};
    }
  }
}

// ---------------- flash attention: MX-scaled fp8 K=128 MFMA, split-K, fixed-max softmax ----
// v4 = v3 with STATIC 128KB LDS (gfx950 allows 160KB/workgroup; removes the dynamic-shared
// + hipFuncSetAttribute launch risk that plausibly killed round 3's container).
// 32 q-rows/wave (2 qg) at 1 block/CU, 1 wave/SIMD -> 512-reg budget (no spill),
// double-buffered 2x64KB LDS with prefetch-next-tile before compute (T3 2-phase).
// K-fragment LDS reads amortized over both qg -> LDS read traffic per q-row halved.
__global__ __launch_bounds__(256, 1) void fa_kernel(
    const u8* __restrict__ qb, const u8* __restrict__ kb, const u8* __restrict__ vTb,
    u8* __restrict__ Opart, float* __restrict__ Lpart, u16* __restrict__ aob, int S) {
  __shared__ u8 smem[131072];
  u8* Ks0 = smem;               // 32 KB: K tile buf0  [128 keys][256B ch, xor-swz]
  u8* Ks1 = smem + 32768;       // 32 KB: K tile buf1
  u8* vT0 = smem + 65536;       // 32 KB: V^T tile buf0 [256 d][128B kpos, xor-swz]
  u8* vT1 = smem + 98304;       // 32 KB: V^T tile buf1
  int by = blockIdx.y;
  int b = by / S, split = by - b * S;
  int t = threadIdx.x, w = t >> 6, lane = t & 63, lo = lane & 15, hi = lane >> 4;
  int qw = blockIdx.x * 128 + w * 32;

  const u8* kb_b = kb + (size_t)b * NN * CC;
  const u8* vb_b = vTb + (size_t)b * CC * NN;
  const int TILES = NN / 128;            // 32
  int jt0 = split * (TILES / S), jt1 = jt0 + TILES / S;

  // stage one 128-key tile (K + V^T) into the given buffers; src pre-swizzled
  auto STAGE = [&](u8* Kd, u8* Vd, int j0) {
#pragma unroll
    for (int i = 0; i < 8; ++i) {
      int base = w * 512 + i * 64;       // wave-uniform slot base
      int sl = base + lane;
      int row = sl >> 4;
      int u = (sl & 15) ^ (row & 7);
      ASYNC16(kb_b + (size_t)(j0 + row) * CC + u * 16, Kd + base * 16);
    }
#pragma unroll
    for (int i = 0; i < 8; ++i) {
      int base = w * 512 + i * 64;
      int sl = base + lane;
      int d = sl >> 3;
      int u = (sl & 7) ^ (d & 7);
      ASYNC16(vb_b + (size_t)d * NN + j0 + u * 16, Vd + base * 16);
    }
  };

  // Q fragments: lane holds query row (qw+qg*16+lo), channels kk*128 + hi*32 + [0..32)
  STAGE(Ks0, vT0, jt0 * 128);            // prologue prefetch overlaps Q loads
  intx8 qf[2][2];
#pragma unroll
  for (int qg = 0; qg < 2; ++qg) {
    const u8* qrow = qb + ((size_t)(b * NN + qw + qg * 16 + lo)) * CC;
#pragma unroll
    for (int kk = 0; kk < 2; ++kk) {
      uint4 a0 = *reinterpret_cast<const uint4*>(qrow + kk * 128 + hi * 32);
      uint4 a1 = *reinterpret_cast<const uint4*>(qrow + kk * 128 + hi * 32 + 16);
      qf[qg][kk] = (intx8){(int)a0.x, (int)a0.y, (int)a0.z, (int)a0.w,
                           (int)a1.x, (int)a1.y, (int)a1.z, (int)a1.w};
    }
  }
  floatx4 oacc[2][16];
#pragma unroll
  for (int qg = 0; qg < 2; ++qg)
#pragma unroll
    for (int dt = 0; dt < 16; ++dt) oacc[qg][dt] = (floatx4){0.f, 0.f, 0.f, 0.f};
  float lacc[2] = {0.f, 0.f};

  auto COMPUTE = [&](const u8* Kp, const u8* Vp) {
    // QK^T + softmax: 8 key-groups of 16; K-fragment shared across both qg
    int pAw[2][8];
#pragma unroll
    for (int g = 0; g < 8; ++g) {
      int row = g * 16 + lo;
      const u8* kr = Kp + row * 256;
      int rs = row & 7;
      floatx4 s0 = (floatx4){0.f, 0.f, 0.f, 0.f};
      floatx4 s1 = (floatx4){0.f, 0.f, 0.f, 0.f};
#pragma unroll
      for (int kk = 0; kk < 2; ++kk) {
        uint4 c0 = *reinterpret_cast<const uint4*>(kr + ((kk * 8 + hi * 2 + 0) ^ rs) * 16);
        uint4 c1 = *reinterpret_cast<const uint4*>(kr + ((kk * 8 + hi * 2 + 1) ^ rs) * 16);
        intx8 kf = (intx8){(int)c0.x, (int)c0.y, (int)c0.z, (int)c0.w,
                           (int)c1.x, (int)c1.y, (int)c1.z, (int)c1.w};
        s0 = __builtin_amdgcn_mfma_scale_f32_16x16x128_f8f6f4(
            kf, qf[0][kk], s0, 0, 0, 0, UNIT_SCALE, 0, UNIT_SCALE);
        s1 = __builtin_amdgcn_mfma_scale_f32_16x16x128_f8f6f4(
            kf, qf[1][kk], s1, 0, 0, 0, UNIT_SCALE, 0, UNIT_SCALE);
      }
      {
        float p0 = __expf(fmaf(s0[0], ATT_SCALE, -MCONST));
        float p1 = __expf(fmaf(s0[1], ATT_SCALE, -MCONST));
        float p2 = __expf(fmaf(s0[2], ATT_SCALE, -MCONST));
        float p3 = __expf(fmaf(s0[3], ATT_SCALE, -MCONST));
        lacc[0] += (p0 + p1) + (p2 + p3);
        pAw[0][g] = (int)pk4f8(p0, p1, p2, p3);  // kpos 32*hi+4*g+b <-> key 16*g+4*hi+b
      }
      {
        float p0 = __expf(fmaf(s1[0], ATT_SCALE, -MCONST));
        float p1 = __expf(fmaf(s1[1], ATT_SCALE, -MCONST));
        float p2 = __expf(fmaf(s1[2], ATT_SCALE, -MCONST));
        float p3 = __expf(fmaf(s1[3], ATT_SCALE, -MCONST));
        lacc[1] += (p0 + p1) + (p2 + p3);
        pAw[1][g] = (int)pk4f8(p0, p1, p2, p3);
      }
    }
    intx8 pA0 = (intx8){pAw[0][0], pAw[0][1], pAw[0][2], pAw[0][3],
                        pAw[0][4], pAw[0][5], pAw[0][6], pAw[0][7]};
    intx8 pA1 = (intx8){pAw[1][0], pAw[1][1], pAw[1][2], pAw[1][3],
                        pAw[1][4], pAw[1][5], pAw[1][6], pAw[1][7]};

    // PV: 128 keys per MFMA; V-fragment shared across both qg
#pragma unroll
    for (int dt = 0; dt < 16; ++dt) {
      int d = dt * 16 + lo;
      const u8* vr = Vp + d * 128;
      int ds7 = d & 7;
      uint4 v0 = *reinterpret_cast<const uint4*>(vr + ((hi * 2 + 0) ^ ds7) * 16);
      uint4 v1 = *reinterpret_cast<const uint4*>(vr + ((hi * 2 + 1) ^ ds7) * 16);
      intx8 vf = (intx8){(int)v0.x, (int)v0.y, (int)v0.z, (int)v0.w,
                         (int)v1.x, (int)v1.y, (int)v1.z, (int)v1.w};
      oacc[0][dt] = __builtin_amdgcn_mfma_scale_f32_16x16x128_f8f6f4(
          pA0, vf, oacc[0][dt], 0, 0, 0, UNIT_SCALE, 0, UNIT_SCALE);
      oacc[1][dt] = __builtin_amdgcn_mfma_scale_f32_16x16x128_f8f6f4(
          pA1, vf, oacc[1][dt], 0, 0, 0, UNIT_SCALE, 0, UNIT_SCALE);
    }
  };

  __syncthreads();                       // prologue tile landed (vmcnt+lgkm drain)
#pragma unroll 1
  for (int jt = jt0; jt < jt1; jt += 2) {
    if (jt + 1 < jt1) STAGE(Ks1, vT1, (jt + 1) * 128);  // prefetch under compute
    COMPUTE(Ks0, vT0);
    __syncthreads();                     // drains prefetch vmem + buf0 reads
    if (jt + 2 < jt1) STAGE(Ks0, vT0, (jt + 2) * 128);
    COMPUTE(Ks1, vT1);
    __syncthreads();
  }

#pragma unroll
  for (int qg = 0; qg < 2; ++qg) {
    lacc[qg] += __shfl_xor(lacc[qg], 16);
    lacc[qg] += __shfl_xor(lacc[qg], 32);
  }

  if (S == 1) {
#pragma unroll
    for (int qg = 0; qg < 2; ++qg) {
      float inv[4];
#pragma unroll
      for (int r = 0; r < 4; ++r) inv[r] = 1.0f / __shfl(lacc[qg], 4 * hi + r);
#pragma unroll
      for (int dt = 0; dt < 16; ++dt)
#pragma unroll
        for (int r = 0; r < 4; ++r) {
          size_t row = (size_t)(b * NN + qw + qg * 16 + 4 * hi + r);
          aob[row * CC + dt * 16 + lo] = f2bf(oacc[qg][dt][r] * inv[r]);
        }
    }
  } else {
    if (hi == 0) {
#pragma unroll
      for (int qg = 0; qg < 2; ++qg)
        Lpart[(size_t)split * M_TOT + b * NN + qw + qg * 16 + lo] = lacc[qg];
    }
    u8* op = Opart + (size_t)split * M_TOT * CC;
#pragma unroll
    for (int qg = 0; qg < 2; ++qg)
#pragma unroll
      for (int dt = 0; dt < 16; ++dt)
#pragma unroll
        for (int r = 0; r < 4; ++r) {
          size_t row = (size_t)(b * NN + qw + qg * 16 + 4 * hi + r);
          op[row * CC + dt * 16 + lo] = f8byte(oacc[qg][dt][r]);
        }
  }
}

// ---------------- proj GEMM + fused fp8 split-K combine + bias + residual -> fp32 out ----
__global__ __launch_bounds__(256) void gemm_proj(
    const u16* __restrict__ aob, const u8* __restrict__ Opart,
    const float* __restrict__ Lpart,
    const u16* __restrict__ wpT, const float* __restrict__ bp,
    const u16* __restrict__ xnb, float* __restrict__ out, int S) {
  __shared__ u16 As[64 * LDT];
  __shared__ u16 Bs[128 * LDT];
  __shared__ float linv[64];
  int m0 = blockIdx.x * 64;
  int n0 = blockIdx.y * 128;
  int t = threadIdx.x, w = t >> 6, lane = t & 63, lo = lane & 15, hi = lane >> 4;
  int wm = (w >> 1) * 32, wn = (w & 1) * 64;
  if (S > 1 && t < 64) {
    float l = 0.f;
    for (int sp = 0; sp < S; ++sp) l += Lpart[(size_t)sp * M_TOT + m0 + t];
    linv[t] = 1.f / l;
  }
  floatx4 acc[2][4];
  for (int i = 0; i < 2; ++i) for (int j = 0; j < 4; ++j) acc[i][j] = (floatx4){0.f, 0.f, 0.f, 0.f};
  for (int kt = 0; kt < 4; ++kt) {
    int k0 = kt * 64;
    __syncthreads();
    for (int i = 0; i < 2; ++i) {
      int c = t + i * 256, r = c >> 3, c8 = c & 7;
      if (S == 1) {
        *reinterpret_cast<uint4*>(As + r * LDT + c8 * 8) =
            *reinterpret_cast<const uint4*>(aob + (size_t)(m0 + r) * CC + k0 + c8 * 8);
      } else {
        float f[8] = {0, 0, 0, 0, 0, 0, 0, 0};
        for (int sp = 0; sp < S; ++sp) {
          uint2 uv = *reinterpret_cast<const uint2*>(
              Opart + (size_t)sp * M_TOT * CC + (size_t)(m0 + r) * CC + k0 + c8 * 8);
          f[0] += __builtin_amdgcn_cvt_f32_fp8(uv.x, 0);
          f[1] += __builtin_amdgcn_cvt_f32_fp8(uv.x, 1);
          f[2] += __builtin_amdgcn_cvt_f32_fp8(uv.x, 2);
          f[3] += __builtin_amdgcn_cvt_f32_fp8(uv.x, 3);
          f[4] += __builtin_amdgcn_cvt_f32_fp8(uv.y, 0);
          f[5] += __builtin_amdgcn_cvt_f32_fp8(uv.y, 1);
          f[6] += __builtin_amdgcn_cvt_f32_fp8(uv.y, 2);
          f[7] += __builtin_amdgcn_cvt_f32_fp8(uv.y, 3);
        }
        float iv = linv[r];
        uint4 o;
        o.x = pack2(f[0] * iv, f[1] * iv); o.y = pack2(f[2] * iv, f[3] * iv);
        o.z = pack2(f[4] * iv, f[5] * iv); o.w = pack2(f[6] * iv, f[7] * iv);
        *reinterpret_cast<uint4*>(As + r * LDT + c8 * 8) = o;
      }
    }
    for (int i = 0; i < 4; ++i) {
      int c = t + i * 256, r = c >> 3, c8 = c & 7;
      *reinterpret_cast<uint4*>(Bs + r * LDT + c8 * 8) =
          *reinterpret_cast<const uint4*>(wpT + (size_t)(n0 + r) * CC + k0 + c8 * 8);
    }
    __syncthreads();
    for (int k32 = 0; k32 < 2; ++k32) {
      short8 af[2], bfr[4];
      for (int mt = 0; mt < 2; ++mt)
        af[mt] = *reinterpret_cast<const short8*>(As + (wm + mt * 16 + lo) * LDT + k32 * 32 + hi * 8);
      for (int nt = 0; nt < 4; ++nt)
        bfr[nt] = *reinterpret_cast<const short8*>(Bs + (wn + nt * 16 + lo) * LDT + k32 * 32 + hi * 8);
      for (int mt = 0; mt < 2; ++mt)
        for (int nt = 0; nt < 4; ++nt)
          acc[mt][nt] = __builtin_amdgcn_mfma_f32_16x16x32_bf16(af[mt], bfr[nt], acc[mt][nt], 0, 0, 0);
    }
  }
  for (int mt = 0; mt < 2; ++mt)
    for (int nt = 0; nt < 4; ++nt)
      for (int r = 0; r < 4; ++r) {
        int row = m0 + wm + mt * 16 + hi * 4 + r;
        int col = n0 + wn + nt * 16 + lo;
        size_t o = (size_t)row * CC + col;
        out[o] = acc[mt][nt][r] + bp[col] + bf2f(xnb[o]);
      }
}

extern "C" void kernel_launch(void* const* d_in, const int* in_sizes, int n_in,
                              void* d_out, int out_size, void* d_ws, size_t ws_size,
                              hipStream_t stream) {
  (void)in_sizes; (void)n_in; (void)out_size;
  const float* x     = (const float*)d_in[0];
  const float* gamma = (const float*)d_in[1];
  const float* beta  = (const float*)d_in[2];
  const float* Wq    = (const float*)d_in[3];
  const float* bq    = (const float*)d_in[4];
  const float* Wk    = (const float*)d_in[5];
  const float* bk    = (const float*)d_in[6];
  const float* Wv    = (const float*)d_in[7];
  const float* bv    = (const float*)d_in[8];
  const float* Wp    = (const float*)d_in[9];
  const float* bp    = (const float*)d_in[10];
  float* out = (float*)d_out;

  char* w = (char*)d_ws;
  float* part  = (float*)w;              w += 512 * NG * 2 * 4;   // 32 KB
  const size_t SZ = (size_t)M_TOT * CC * 2;   // 8 MB bf16 tensor
  const size_t SZ8 = (size_t)M_TOT * CC;      // 4 MB fp8 tensor
  u16* xnb = (u16*)w; w += SZ;
  u8* qb   = (u8*)w;  w += SZ8;
  u8* kb   = (u8*)w;  w += SZ8;
  u8* vTb  = (u8*)w;  w += SZ8;
  u16* aob = (u16*)w; w += SZ;
  u16* wqT = (u16*)w; w += (size_t)CC * CC * 2;
  u16* wkT = (u16*)w; w += (size_t)CC * CC * 2;
  u16* wvT = (u16*)w; w += (size_t)CC * CC * 2;
  u16* wpT = (u16*)w; w += (size_t)CC * CC * 2;

  size_t used = (size_t)(w - (char*)d_ws);
  size_t per_split = SZ8 + (size_t)M_TOT * 4 + 256;
  int S = 2;                              // 32 x 8 = 256 blocks = 1/CU, single round
  if (used + 2 * per_split > ws_size) S = 1;
  u8* Opart = (u8*)w;                    w += (size_t)S * SZ8;
  float* Lpart = (float*)w;

  prep_stats<<<576, 256, 0, stream>>>(x, Wq, Wk, Wv, Wp, part, wqT, wkT, wvT, wpT);
  gn_apply<<<512, 256, 0, stream>>>(x, gamma, beta, part, xnb);
  gemm_qkv<<<dim3(M_TOT / 128, 6), 256, 0, stream>>>(xnb, wqT, wkT, wvT, bq, bk, bv, qb, kb, vTb);
  fa_kernel<<<dim3(NN / 128, BB * S), 256, 0, stream>>>(qb, kb, vTb, Opart, Lpart, aob, S);
  gemm_proj<<<dim3(M_TOT / 64, 2), 256, 0, stream>>>(aob, Opart, Lpart, wpT, bp, xnb, out, S);
}

// Round 5
// 180.203 us; speedup vs baseline: 1.3251x; 1.3251x over previous
//
#include <hip/hip_runtime.h>
#include <hip/hip_bf16.h>

typedef unsigned short u16;
typedef unsigned char u8;
typedef short short8 __attribute__((ext_vector_type(8)));
typedef float floatx4 __attribute__((ext_vector_type(4)));
typedef int intx8 __attribute__((ext_vector_type(8)));
typedef long long i64;

#define BB 4
#define NN 4096
#define CC 256
#define NG 8
#define M_TOT (BB * NN)   // 16384 rows
#define GN_EPS 1e-3f
#define ATT_SCALE 0.0625f // C^-0.5
#define MCONST 2.5f       // fixed softmax offset: keeps p=exp(s'-MCONST) in fp8 normal range
#define UNIT_SCALE 0x7F7F7F7F  // E8M0 127 in every byte -> scale 1.0

__device__ __forceinline__ u16 f2bf(float f) {
  __hip_bfloat16 h = __float2bfloat16(f);
  return __builtin_bit_cast(u16, h);
}
__device__ __forceinline__ float bf2f(u16 u) {
  unsigned int i = ((unsigned int)u) << 16;
  return __builtin_bit_cast(float, i);
}
__device__ __forceinline__ unsigned pack2(float a, float b) {
  return (unsigned)f2bf(a) | ((unsigned)f2bf(b) << 16);
}
// pack 4 floats -> 4 fp8 e4m3 bytes
__device__ __forceinline__ unsigned pk4f8(float a, float b, float c, float d) {
  unsigned v = __builtin_amdgcn_cvt_pk_fp8_f32(a, b, 0, false);
  v = __builtin_amdgcn_cvt_pk_fp8_f32(c, d, v, true);
  return v;
}
__device__ __forceinline__ u8 f8byte(float a) {
  return (u8)(__builtin_amdgcn_cvt_pk_fp8_f32(a, a, 0, false) & 0xFF);
}

typedef __attribute__((address_space(3))) unsigned int lds_u32;
typedef const __attribute__((address_space(1))) unsigned int glb_u32;
#define ASYNC16(g, l) \
  __builtin_amdgcn_global_load_lds((glb_u32*)(g), (lds_u32*)(l), 16, 0, 0)

// ---------------- fused: GN stats partials (blocks 0..511) + weight transpose (512..575) ----
__global__ void prep_stats(const float* __restrict__ x,
                           const float* __restrict__ Wq, const float* __restrict__ Wk,
                           const float* __restrict__ Wv, const float* __restrict__ Wp,
                           float* __restrict__ part,
                           u16* __restrict__ wqT, u16* __restrict__ wkT,
                           u16* __restrict__ wvT, u16* __restrict__ wpT) {
  __shared__ u16 Ts[64][68];
  int blk = blockIdx.x;
  int t = threadIdx.x;
  if (blk < 512) {
    int b = blk >> 7, chunk = blk & 127;
    const float* p = x + ((size_t)b * NN + chunk * 32) * CC + t;
    float s = 0.f, ss = 0.f;
    for (int i = 0; i < 32; ++i) { float v = p[(size_t)i * CC]; s += v; ss += v * v; }
    for (int off = 1; off < 32; off <<= 1) { s += __shfl_xor(s, off); ss += __shfl_xor(ss, off); }
    if ((t & 31) == 0) {
      int g = t >> 5;
      part[((size_t)blk * NG + g) * 2 + 0] = s;
      part[((size_t)blk * NG + g) * 2 + 1] = ss;
    }
  } else {
    int pid = blk - 512;
    int y = pid >> 4, tile = pid & 15;
    int o0 = (tile >> 2) * 64, c0 = (tile & 3) * 64;
    const float* W = (y == 0) ? Wq : (y == 1) ? Wk : (y == 2) ? Wv : Wp;
    u16* WT = (y == 0) ? wqT : (y == 1) ? wkT : (y == 2) ? wvT : wpT;
    int cl = t >> 4, o4 = t & 15;
    for (int it = 0; it < 4; ++it) {
      int c = cl + it * 16;
      float4 v = *reinterpret_cast<const float4*>(W + (size_t)(c0 + c) * CC + o0 + o4 * 4);
      Ts[c][o4 * 4 + 0] = f2bf(v.x); Ts[c][o4 * 4 + 1] = f2bf(v.y);
      Ts[c][o4 * 4 + 2] = f2bf(v.z); Ts[c][o4 * 4 + 3] = f2bf(v.w);
    }
    __syncthreads();
    int ol = t >> 3, c8 = t & 7;
    for (int it = 0; it < 2; ++it) {
      int o = ol + it * 32;
      uint4 uv;
      uv.x = (unsigned)Ts[c8 * 8 + 0][o] | ((unsigned)Ts[c8 * 8 + 1][o] << 16);
      uv.y = (unsigned)Ts[c8 * 8 + 2][o] | ((unsigned)Ts[c8 * 8 + 3][o] << 16);
      uv.z = (unsigned)Ts[c8 * 8 + 4][o] | ((unsigned)Ts[c8 * 8 + 5][o] << 16);
      uv.w = (unsigned)Ts[c8 * 8 + 6][o] | ((unsigned)Ts[c8 * 8 + 7][o] << 16);
      *reinterpret_cast<uint4*>(WT + (size_t)(o0 + o) * CC + c0 + c8 * 8) = uv;
    }
  }
}

// ---------------- GroupNorm: inline finalize (from partials) + apply -> xn bf16 ----------
__global__ __launch_bounds__(256) void gn_apply(
    const float* __restrict__ x, const float* __restrict__ gamma,
    const float* __restrict__ beta, const float* __restrict__ part,
    u16* __restrict__ xnb) {
  __shared__ float gnst[16];
  int blk = blockIdx.x;
  int t = threadIdx.x;
  int b = blk >> 7;                      // 128 blocks per batch
  if (t < 64) {
    int g = t >> 3, j = t & 7;
    float s = 0.f, ss = 0.f;
    for (int ch = j; ch < 128; ch += 8) {
      size_t idx = (((size_t)(b * 128 + ch)) * NG + g) * 2;
      s += part[idx]; ss += part[idx + 1];
    }
    for (int off = 1; off < 8; off <<= 1) { s += __shfl_xor(s, off); ss += __shfl_xor(ss, off); }
    if (j == 0) {
      const float cnt = (float)(NN * (CC / NG));
      float mean = s / cnt;
      float var = ss / cnt - mean * mean;
      gnst[g * 2] = mean;
      gnst[g * 2 + 1] = rsqrtf(var + GN_EPS);
    }
  }
  __syncthreads();
  int row0 = blk * 32;
#pragma unroll
  for (int it = 0; it < 8; ++it) {
    int idx = t + it * 256;              // 0..2047: 32 rows x 64 float4
    int rl = idx >> 6, c4 = idx & 63;
    int g = c4 >> 3;
    float mean = gnst[g * 2], rstd = gnst[g * 2 + 1];
    size_t gidx = (size_t)(row0 + rl) * 64 + c4;
    float4 v = reinterpret_cast<const float4*>(x)[gidx];
    float4 gm = reinterpret_cast<const float4*>(gamma)[c4];
    float4 bt = reinterpret_cast<const float4*>(beta)[c4];
    ushort4 o;
    o.x = f2bf((v.x - mean) * rstd * gm.x + bt.x);
    o.y = f2bf((v.y - mean) * rstd * gm.y + bt.y);
    o.z = f2bf((v.z - mean) * rstd * gm.z + bt.z);
    o.w = f2bf((v.w - mean) * rstd * gm.w + bt.w);
    reinterpret_cast<ushort4*>(xnb)[gidx] = o;
  }
}

// ---------------- fused QKV GEMM (bf16 compute, fp8 outputs) ----------------
// q,k: natural fp8 [B][N][C].
// v: fp8 [B][C=d][N], per 128-token tile permuted so that k-position p holds
//    token key(p) = 16*((p>>2)&7) + 4*(p>>5) + (p&3)  (matches K=128 scaled-MFMA
//    A-fragment packing of P in fa_kernel: kpos 32*hi+4*g+b <-> key 16*g+4*hi+b).
#define LDT 72
__global__ __launch_bounds__(256) void gemm_qkv(
    const u16* __restrict__ xnb,
    const u16* __restrict__ wqT, const u16* __restrict__ wkT, const u16* __restrict__ wvT,
    const float* __restrict__ bq, const float* __restrict__ bk, const float* __restrict__ bv,
    u8* __restrict__ qb, u8* __restrict__ kb, u8* __restrict__ vTb) {
  __shared__ u16 sm[2 * 128 * LDT];
  u16* Asp = sm;
  u16* Bsp = sm + 128 * LDT;
  int m0 = blockIdx.x * 128;
  int widx = blockIdx.y >> 1;
  int n0 = (blockIdx.y & 1) * 128;
  const u16* wT = (widx == 0) ? wqT : (widx == 1) ? wkT : wvT;
  const float* bias = (widx == 0) ? bq : (widx == 1) ? bk : bv;
  int t = threadIdx.x, w = t >> 6, lane = t & 63, lo = lane & 15, hi = lane >> 4;
  int wm = (w >> 1) * 64, wn = (w & 1) * 64;
  floatx4 acc[4][4];
  for (int i = 0; i < 4; ++i) for (int j = 0; j < 4; ++j) acc[i][j] = (floatx4){0.f, 0.f, 0.f, 0.f};
  for (int kt = 0; kt < 4; ++kt) {
    int k0 = kt * 64;
    __syncthreads();
    for (int i = 0; i < 4; ++i) {
      int idx = t + i * 256, r = idx >> 3, c8 = idx & 7;
      *reinterpret_cast<uint4*>(Asp + r * LDT + c8 * 8) =
          *reinterpret_cast<const uint4*>(xnb + (size_t)(m0 + r) * CC + k0 + c8 * 8);
      *reinterpret_cast<uint4*>(Bsp + r * LDT + c8 * 8) =
          *reinterpret_cast<const uint4*>(wT + (size_t)(n0 + r) * CC + k0 + c8 * 8);
    }
    __syncthreads();
    for (int k32 = 0; k32 < 2; ++k32) {
      short8 af[4], bfr[4];
      for (int mt = 0; mt < 4; ++mt)
        af[mt] = *reinterpret_cast<const short8*>(Asp + (wm + mt * 16 + lo) * LDT + k32 * 32 + hi * 8);
      for (int nt = 0; nt < 4; ++nt)
        bfr[nt] = *reinterpret_cast<const short8*>(Bsp + (wn + nt * 16 + lo) * LDT + k32 * 32 + hi * 8);
      for (int mt = 0; mt < 4; ++mt)
        for (int nt = 0; nt < 4; ++nt)
          acc[mt][nt] = __builtin_amdgcn_mfma_f32_16x16x32_bf16(af[mt], bfr[nt], acc[mt][nt], 0, 0, 0);
    }
  }
  __syncthreads();
  for (int mt = 0; mt < 4; ++mt)
    for (int nt = 0; nt < 4; ++nt)
      for (int r = 0; r < 4; ++r) {
        int rr = wm + mt * 16 + hi * 4 + r;
        int cc2 = wn + nt * 16 + lo;
        sm[rr * 130 + cc2] = f2bf(acc[mt][nt][r] + bias[n0 + cc2]);
      }
  __syncthreads();
  if (widx < 2) {
    u8* outp = (widx == 0) ? qb : kb;
    for (int j = 0; j < 8; ++j) {
      int c = t + j * 256;
      int row = c >> 4, chl = c & 15;
      const u16* sp = sm + row * 130 + chl * 8;
      uint2 val;
      val.x = pk4f8(bf2f(sp[0]), bf2f(sp[1]), bf2f(sp[2]), bf2f(sp[3]));
      val.y = pk4f8(bf2f(sp[4]), bf2f(sp[5]), bf2f(sp[6]), bf2f(sp[7]));
      int rowg = m0 + row;
      int chg = (n0 >> 3) + chl;
      *reinterpret_cast<uint2*>(outp + (size_t)rowg * CC + chg * 8) = val;
    }
  } else {
    // V writer: block covers tokens [m0, m0+128) = exactly one 128-key tile.
    // 16B chunk (dloc, u): byte c holds V[key][dglob] with
    //   key = 64*(u&1) + 4*(u>>1) + 16*(c>>2) + (c&3)
    int dloc = t & 127;
    int dglob = n0 + dloc;
    int bb = m0 >> 12, tk = m0 & (NN - 1);
    u8* dst = vTb + ((size_t)(bb * CC + dglob)) * NN + tk;
#pragma unroll
    for (int it = 0; it < 2; ++it) {
      int ub = (t >> 7) * 2 + it * 4;    // {0,4} or {2,6}; covers u=ub,ub+1
      unsigned wds[8];
#pragma unroll
      for (int uo = 0; uo < 2; ++uo) {
        int u = ub + uo;
        int rbase = 64 * (u & 1) + 4 * (u >> 1);
#pragma unroll
        for (int q = 0; q < 4; ++q) {
          int r0 = rbase + q * 16;
          wds[uo * 4 + q] = pk4f8(bf2f(sm[(r0 + 0) * 130 + dloc]), bf2f(sm[(r0 + 1) * 130 + dloc]),
                                  bf2f(sm[(r0 + 2) * 130 + dloc]), bf2f(sm[(r0 + 3) * 130 + dloc]));
        }
      }
      *reinterpret_cast<uint4*>(dst + ub * 16) = (uint4){wds[0], wds[1], wds[2], wds[3]};
      *reinterpret_cast<uint4*>(dst + ub * 16 + 16) = (uint4){wds[4], wds[5], wds[6], wds[7]};
    }
  }
}

// ---------------- flash attention: MX-scaled fp8 K=128 MFMA, split-K, fixed-max softmax ----
// v5 = v4 (32 q-rows/wave, 1 block/CU, 2x64KB dbuf, static LDS) with the arch-VGPR
// pressure removed: staging addresses reduced to 3 hoisted per-lane offsets + constant
// strides (algebraically identical to the verified v2/v4 addressing), and a single
// STAGE+COMPUTE loop body with ping-pong pointer swap (no 2x inlined copies).
// Round-4 evidence: VGPR=256 cap + ~35 dword/thread scratch -> the 16 recomputed
// ASYNC16 address chains were the spill source.
__global__ __launch_bounds__(256, 1) void fa_kernel(
    const u8* __restrict__ qb, const u8* __restrict__ kb, const u8* __restrict__ vTb,
    u8* __restrict__ Opart, float* __restrict__ Lpart, u16* __restrict__ aob, int S) {
  __shared__ u8 smem[131072];
  int by = blockIdx.y;
  int b = by / S, split = by - b * S;
  int t = threadIdx.x, w = t >> 6, lane = t & 63, lo = lane & 15, hi = lane >> 4;
  int qw = blockIdx.x * 128 + w * 32;

  const u8* kb_b = kb + (size_t)b * NN * CC;
  const u8* vb_b = vTb + (size_t)b * CC * NN;
  const int TILES = NN / 128;            // 32
  int jt0 = split * (TILES / S), jt1 = jt0 + TILES / S;

  // hoisted per-lane staging offsets (verified-identical to v2/v4 addressing):
  // K slot i: row = w*32 + i*4 + hi, u = lo ^ ((i*4+hi)&7); i even/odd collapse to
  // two offsets + stride 2048 per i-pair. V slot i: d = w*64 + i*8 + (lane>>3),
  // u = (lane&7)^((lane>>3)&7); one offset + stride 32768.
  int koffE = ((w << 5) + hi) * CC + ((lo ^ hi) << 4);
  int koffO = ((w << 5) + 4 + hi) * CC + ((lo ^ hi ^ 4) << 4);
  int voff  = ((w << 6) + (lane >> 3)) * NN + ((((lane & 7) ^ ((lane >> 3) & 7))) << 4);
  int ldsb  = (w * 512) * 16;            // wave-uniform LDS base (bytes)

  auto STAGE = [&](u8* Kd, u8* Vd, int j0) {
    const u8* ksrc = kb_b + (size_t)j0 * CC;
    const u8* vsrc = vb_b + j0 + voff;
#pragma unroll
    for (int i2 = 0; i2 < 4; ++i2) {
      ASYNC16(ksrc + koffE + i2 * 2048, Kd + ldsb + (2 * i2) * 1024);
      ASYNC16(ksrc + koffO + i2 * 2048, Kd + ldsb + (2 * i2 + 1) * 1024);
    }
#pragma unroll
    for (int i = 0; i < 8; ++i)
      ASYNC16(vsrc + i * 32768, Vd + ldsb + i * 1024);
  };

  u8* Ka = smem;                // current K buf
  u8* Kn = smem + 32768;        // next K buf
  u8* Va = smem + 65536;        // current V^T buf
  u8* Vn = smem + 98304;        // next V^T buf

  STAGE(Ka, Va, jt0 * 128);     // prologue prefetch overlaps Q loads

  // Q fragments: lane holds query row (qw+qg*16+lo), channels kk*128 + hi*32 + [0..32)
  intx8 qf[2][2];
#pragma unroll
  for (int qg = 0; qg < 2; ++qg) {
    const u8* qrow = qb + ((size_t)(b * NN + qw + qg * 16 + lo)) * CC;
#pragma unroll
    for (int kk = 0; kk < 2; ++kk) {
      uint4 a0 = *reinterpret_cast<const uint4*>(qrow + kk * 128 + hi * 32);
      uint4 a1 = *reinterpret_cast<const uint4*>(qrow + kk * 128 + hi * 32 + 16);
      qf[qg][kk] = (intx8){(int)a0.x, (int)a0.y, (int)a0.z, (int)a0.w,
                           (int)a1.x, (int)a1.y, (int)a1.z, (int)a1.w};
    }
  }
  floatx4 oacc[2][16];
#pragma unroll
  for (int qg = 0; qg < 2; ++qg)
#pragma unroll
    for (int dt = 0; dt < 16; ++dt) oacc[qg][dt] = (floatx4){0.f, 0.f, 0.f, 0.f};
  float lacc[2] = {0.f, 0.f};

  auto COMPUTE = [&](const u8* Kp, const u8* Vp) {
    // QK^T + softmax: 8 key-groups of 16; K-fragment shared across both qg
    int pAw[2][8];
#pragma unroll
    for (int g = 0; g < 8; ++g) {
      int row = g * 16 + lo;
      const u8* kr = Kp + row * 256;
      int rs = row & 7;
      floatx4 s0 = (floatx4){0.f, 0.f, 0.f, 0.f};
      floatx4 s1 = (floatx4){0.f, 0.f, 0.f, 0.f};
#pragma unroll
      for (int kk = 0; kk < 2; ++kk) {
        uint4 c0 = *reinterpret_cast<const uint4*>(kr + ((kk * 8 + hi * 2 + 0) ^ rs) * 16);
        uint4 c1 = *reinterpret_cast<const uint4*>(kr + ((kk * 8 + hi * 2 + 1) ^ rs) * 16);
        intx8 kf = (intx8){(int)c0.x, (int)c0.y, (int)c0.z, (int)c0.w,
                           (int)c1.x, (int)c1.y, (int)c1.z, (int)c1.w};
        s0 = __builtin_amdgcn_mfma_scale_f32_16x16x128_f8f6f4(
            kf, qf[0][kk], s0, 0, 0, 0, UNIT_SCALE, 0, UNIT_SCALE);
        s1 = __builtin_amdgcn_mfma_scale_f32_16x16x128_f8f6f4(
            kf, qf[1][kk], s1, 0, 0, 0, UNIT_SCALE, 0, UNIT_SCALE);
      }
      {
        float p0 = __expf(fmaf(s0[0], ATT_SCALE, -MCONST));
        float p1 = __expf(fmaf(s0[1], ATT_SCALE, -MCONST));
        float p2 = __expf(fmaf(s0[2], ATT_SCALE, -MCONST));
        float p3 = __expf(fmaf(s0[3], ATT_SCALE, -MCONST));
        lacc[0] += (p0 + p1) + (p2 + p3);
        pAw[0][g] = (int)pk4f8(p0, p1, p2, p3);  // kpos 32*hi+4*g+b <-> key 16*g+4*hi+b
      }
      {
        float p0 = __expf(fmaf(s1[0], ATT_SCALE, -MCONST));
        float p1 = __expf(fmaf(s1[1], ATT_SCALE, -MCONST));
        float p2 = __expf(fmaf(s1[2], ATT_SCALE, -MCONST));
        float p3 = __expf(fmaf(s1[3], ATT_SCALE, -MCONST));
        lacc[1] += (p0 + p1) + (p2 + p3);
        pAw[1][g] = (int)pk4f8(p0, p1, p2, p3);
      }
    }
    intx8 pA0 = (intx8){pAw[0][0], pAw[0][1], pAw[0][2], pAw[0][3],
                        pAw[0][4], pAw[0][5], pAw[0][6], pAw[0][7]};
    intx8 pA1 = (intx8){pAw[1][0], pAw[1][1], pAw[1][2], pAw[1][3],
                        pAw[1][4], pAw[1][5], pAw[1][6], pAw[1][7]};

    // PV: 128 keys per MFMA; V-fragment shared across both qg
#pragma unroll
    for (int dt = 0; dt < 16; ++dt) {
      int d = dt * 16 + lo;
      const u8* vr = Vp + d * 128;
      int ds7 = d & 7;
      uint4 v0 = *reinterpret_cast<const uint4*>(vr + ((hi * 2 + 0) ^ ds7) * 16);
      uint4 v1 = *reinterpret_cast<const uint4*>(vr + ((hi * 2 + 1) ^ ds7) * 16);
      intx8 vf = (intx8){(int)v0.x, (int)v0.y, (int)v0.z, (int)v0.w,
                         (int)v1.x, (int)v1.y, (int)v1.z, (int)v1.w};
      oacc[0][dt] = __builtin_amdgcn_mfma_scale_f32_16x16x128_f8f6f4(
          pA0, vf, oacc[0][dt], 0, 0, 0, UNIT_SCALE, 0, UNIT_SCALE);
      oacc[1][dt] = __builtin_amdgcn_mfma_scale_f32_16x16x128_f8f6f4(
          pA1, vf, oacc[1][dt], 0, 0, 0, UNIT_SCALE, 0, UNIT_SCALE);
    }
  };

  __syncthreads();                       // prologue tile landed (vmcnt+lgkm drain)
  for (int jt = jt0; jt < jt1; ++jt) {
    if (jt + 1 < jt1) STAGE(Kn, Vn, (jt + 1) * 128);  // prefetch under compute
    COMPUTE(Ka, Va);
    __syncthreads();                     // all reads of (Ka,Va) done; (Kn,Vn) landed
    u8* tk = Ka; Ka = Kn; Kn = tk;
    u8* tv = Va; Va = Vn; Vn = tv;
  }

#pragma unroll
  for (int qg = 0; qg < 2; ++qg) {
    lacc[qg] += __shfl_xor(lacc[qg], 16);
    lacc[qg] += __shfl_xor(lacc[qg], 32);
  }

  if (S == 1) {
#pragma unroll
    for (int qg = 0; qg < 2; ++qg) {
      float inv[4];
#pragma unroll
      for (int r = 0; r < 4; ++r) inv[r] = 1.0f / __shfl(lacc[qg], 4 * hi + r);
#pragma unroll
      for (int dt = 0; dt < 16; ++dt)
#pragma unroll
        for (int r = 0; r < 4; ++r) {
          size_t row = (size_t)(b * NN + qw + qg * 16 + 4 * hi + r);
          aob[row * CC + dt * 16 + lo] = f2bf(oacc[qg][dt][r] * inv[r]);
        }
    }
  } else {
    if (hi == 0) {
#pragma unroll
      for (int qg = 0; qg < 2; ++qg)
        Lpart[(size_t)split * M_TOT + b * NN + qw + qg * 16 + lo] = lacc[qg];
    }
    u8* op = Opart + (size_t)split * M_TOT * CC;
#pragma unroll
    for (int qg = 0; qg < 2; ++qg)
#pragma unroll
      for (int dt = 0; dt < 16; ++dt)
#pragma unroll
        for (int r = 0; r < 4; ++r) {
          size_t row = (size_t)(b * NN + qw + qg * 16 + 4 * hi + r);
          op[row * CC + dt * 16 + lo] = f8byte(oacc[qg][dt][r]);
        }
  }
}

// ---------------- proj GEMM + fused fp8 split-K combine + bias + residual -> fp32 out ----
__global__ __launch_bounds__(256) void gemm_proj(
    const u16* __restrict__ aob, const u8* __restrict__ Opart,
    const float* __restrict__ Lpart,
    const u16* __restrict__ wpT, const float* __restrict__ bp,
    const u16* __restrict__ xnb, float* __restrict__ out, int S) {
  __shared__ u16 As[64 * LDT];
  __shared__ u16 Bs[128 * LDT];
  __shared__ float linv[64];
  int m0 = blockIdx.x * 64;
  int n0 = blockIdx.y * 128;
  int t = threadIdx.x, w = t >> 6, lane = t & 63, lo = lane & 15, hi = lane >> 4;
  int wm = (w >> 1) * 32, wn = (w & 1) * 64;
  if (S > 1 && t < 64) {
    float l = 0.f;
    for (int sp = 0; sp < S; ++sp) l += Lpart[(size_t)sp * M_TOT + m0 + t];
    linv[t] = 1.f / l;
  }
  floatx4 acc[2][4];
  for (int i = 0; i < 2; ++i) for (int j = 0; j < 4; ++j) acc[i][j] = (floatx4){0.f, 0.f, 0.f, 0.f};
  for (int kt = 0; kt < 4; ++kt) {
    int k0 = kt * 64;
    __syncthreads();
    for (int i = 0; i < 2; ++i) {
      int c = t + i * 256, r = c >> 3, c8 = c & 7;
      if (S == 1) {
        *reinterpret_cast<uint4*>(As + r * LDT + c8 * 8) =
            *reinterpret_cast<const uint4*>(aob + (size_t)(m0 + r) * CC + k0 + c8 * 8);
      } else {
        float f[8] = {0, 0, 0, 0, 0, 0, 0, 0};
        for (int sp = 0; sp < S; ++sp) {
          uint2 uv = *reinterpret_cast<const uint2*>(
              Opart + (size_t)sp * M_TOT * CC + (size_t)(m0 + r) * CC + k0 + c8 * 8);
          f[0] += __builtin_amdgcn_cvt_f32_fp8(uv.x, 0);
          f[1] += __builtin_amdgcn_cvt_f32_fp8(uv.x, 1);
          f[2] += __builtin_amdgcn_cvt_f32_fp8(uv.x, 2);
          f[3] += __builtin_amdgcn_cvt_f32_fp8(uv.x, 3);
          f[4] += __builtin_amdgcn_cvt_f32_fp8(uv.y, 0);
          f[5] += __builtin_amdgcn_cvt_f32_fp8(uv.y, 1);
          f[6] += __builtin_amdgcn_cvt_f32_fp8(uv.y, 2);
          f[7] += __builtin_amdgcn_cvt_f32_fp8(uv.y, 3);
        }
        float iv = linv[r];
        uint4 o;
        o.x = pack2(f[0] * iv, f[1] * iv); o.y = pack2(f[2] * iv, f[3] * iv);
        o.z = pack2(f[4] * iv, f[5] * iv); o.w = pack2(f[6] * iv, f[7] * iv);
        *reinterpret_cast<uint4*>(As + r * LDT + c8 * 8) = o;
      }
    }
    for (int i = 0; i < 4; ++i) {
      int c = t + i * 256, r = c >> 3, c8 = c & 7;
      *reinterpret_cast<uint4*>(Bs + r * LDT + c8 * 8) =
          *reinterpret_cast<const uint4*>(wpT + (size_t)(n0 + r) * CC + k0 + c8 * 8);
    }
    __syncthreads();
    for (int k32 = 0; k32 < 2; ++k32) {
      short8 af[2], bfr[4];
      for (int mt = 0; mt < 2; ++mt)
        af[mt] = *reinterpret_cast<const short8*>(As + (wm + mt * 16 + lo) * LDT + k32 * 32 + hi * 8);
      for (int nt = 0; nt < 4; ++nt)
        bfr[nt] = *reinterpret_cast<const short8*>(Bs + (wn + nt * 16 + lo) * LDT + k32 * 32 + hi * 8);
      for (int mt = 0; mt < 2; ++mt)
        for (int nt = 0; nt < 4; ++nt)
          acc[mt][nt] = __builtin_amdgcn_mfma_f32_16x16x32_bf16(af[mt], bfr[nt], acc[mt][nt], 0, 0, 0);
    }
  }
  for (int mt = 0; mt < 2; ++mt)
    for (int nt = 0; nt < 4; ++nt)
      for (int r = 0; r < 4; ++r) {
        int row = m0 + wm + mt * 16 + hi * 4 + r;
        int col = n0 + wn + nt * 16 + lo;
        size_t o = (size_t)row * CC + col;
        out[o] = acc[mt][nt][r] + bp[col] + bf2f(xnb[o]);
      }
}

extern "C" void kernel_launch(void* const* d_in, const int* in_sizes, int n_in,
                              void* d_out, int out_size, void* d_ws, size_t ws_size,
                              hipStream_t stream) {
  (void)in_sizes; (void)n_in; (void)out_size;
  const float* x     = (const float*)d_in[0];
  const float* gamma = (const float*)d_in[1];
  const float* beta  = (const float*)d_in[2];
  const float* Wq    = (const float*)d_in[3];
  const float* bq    = (const float*)d_in[4];
  const float* Wk    = (const float*)d_in[5];
  const float* bk    = (const float*)d_in[6];
  const float* Wv    = (const float*)d_in[7];
  const float* bv    = (const float*)d_in[8];
  const float* Wp    = (const float*)d_in[9];
  const float* bp    = (const float*)d_in[10];
  float* out = (float*)d_out;

  char* w = (char*)d_ws;
  float* part  = (float*)w;              w += 512 * NG * 2 * 4;   // 32 KB
  const size_t SZ = (size_t)M_TOT * CC * 2;   // 8 MB bf16 tensor
  const size_t SZ8 = (size_t)M_TOT * CC;      // 4 MB fp8 tensor
  u16* xnb = (u16*)w; w += SZ;
  u8* qb   = (u8*)w;  w += SZ8;
  u8* kb   = (u8*)w;  w += SZ8;
  u8* vTb  = (u8*)w;  w += SZ8;
  u16* aob = (u16*)w; w += SZ;
  u16* wqT = (u16*)w; w += (size_t)CC * CC * 2;
  u16* wkT = (u16*)w; w += (size_t)CC * CC * 2;
  u16* wvT = (u16*)w; w += (size_t)CC * CC * 2;
  u16* wpT = (u16*)w; w += (size_t)CC * CC * 2;

  size_t used = (size_t)(w - (char*)d_ws);
  size_t per_split = SZ8 + (size_t)M_TOT * 4 + 256;
  int S = 2;                              // 32 x 8 = 256 blocks = 1/CU, single round
  if (used + 2 * per_split > ws_size) S = 1;
  u8* Opart = (u8*)w;                    w += (size_t)S * SZ8;
  float* Lpart = (float*)w;

  prep_stats<<<576, 256, 0, stream>>>(x, Wq, Wk, Wv, Wp, part, wqT, wkT, wvT, wpT);
  gn_apply<<<512, 256, 0, stream>>>(x, gamma, beta, part, xnb);
  gemm_qkv<<<dim3(M_TOT / 128, 6), 256, 0, stream>>>(xnb, wqT, wkT, wvT, bq, bk, bv, qb, kb, vTb);
  fa_kernel<<<dim3(NN / 128, BB * S), 256, 0, stream>>>(qb, kb, vTb, Opart, Lpart, aob, S);
  gemm_proj<<<dim3(M_TOT / 64, 2), 256, 0, stream>>>(aob, Opart, Lpart, wpT, bp, xnb, out, S);
}